// Round 19
// baseline (103.363 us; speedup 1.0000x reference)
//
#include <hip/hip_runtime.h>

// Problem constants: B=32, L=2, F=65536, D=768
#define BB 32
#define LL 2
#define FF 65536
#define DD 768
#define F4 (FF / 4)        // 16384 float4 per f row
#define LD (LL * DD)       // 1536
#define BL (BB * LD)       // 49152 outputs

#define NSTEPS (FF / 16)   // 4096 K16-steps
#define APREP_BYTES ((size_t)NSTEPS * 64 * 16)      // 4 MB
#define CHUNK_BYTES ((size_t)BL * sizeof(float))    // 196608 B
#define NF 128             // F-chunks (split-K)
#define KS (NSTEPS / NF)   // 32 K16-steps per chunk

typedef __attribute__((ext_vector_type(8)))  short short8;   // 8 bf16 (4 VGPR)
typedef __attribute__((ext_vector_type(16))) float float16;  // 16 fp32 acc

// fp32 -> bf16 round-to-nearest-even (finite inputs)
static __device__ __forceinline__ unsigned bf16rne(float x)
{
    unsigned u = __float_as_uint(x);
    return (u + 0x7fffu + ((u >> 16) & 1u)) >> 16;
}
static __device__ __forceinline__ unsigned packbf(float a, float b)
{
    return bf16rne(a) | (bf16rne(b) << 16);
}

// Prep: build A-fragments. aprep[s][lane] (uint4) = 8 bf16 of
// A[row = lane&31][k = s*16 + (lane>>5)*8 + j], j=0..7, A[b][k] = f[b][k].
__global__ __launch_bounds__(256) void cc_prep_a(
    const float4* __restrict__ f4,     // [32][16384]
    uint4* __restrict__ aprep)         // [4096][64]
{
    int t = blockIdx.x * 256 + threadIdx.x;      // 0 .. 4096*64-1
    if (t >= NSTEPS * 64) return;
    int s = t >> 6;
    int l = t & 63;
    int b = l & 31;
    int k0 = s * 16 + ((l >> 5) << 3);           // multiple of 8
    float4 fa = f4[(size_t)b * F4 + (k0 >> 2)];
    float4 fb = f4[(size_t)b * F4 + (k0 >> 2) + 1];
    uint4 u;
    u.x = packbf(fa.x, fa.y);
    u.y = packbf(fa.z, fa.w);
    u.z = packbf(fb.x, fb.y);
    u.w = packbf(fb.z, fb.w);
    aprep[t] = u;
}

// Stage 1: MFMA partial GEMM, dwordx2 weight loads via even/odd n-tiles.
// grid = (24, NF); block = 64 (one wave).
// Wave tile: M=32 x 64 d's (even tile: d = d0+2n, odd tile: d = d0+2n+1).
// Per K16-step: 1 dwordx4 A-frag + 8 dwordx2 weight loads (each 512B
// CONTIGUOUS) + 16 bf16 cvts + 2 mfma_32x32x16_bf16.
// acc 32 VGPR -> ~75 total; (64,4) cap 128 (proven spill-free class).
// C/D layout: n = lane&31, row b = (r&3) + 8*(r>>2) + 4*(lane>>5); the
// (even,odd) pair (acc0[r],acc1[r]) is written as one coalesced float2.
__global__ __launch_bounds__(64, 4) void cc_mfma(
    const uint4* __restrict__ aprep,   // [4096][64]
    const float* __restrict__ weight,  // [2][65536][768]
    float* __restrict__ partials)      // [NF][32][1536]
{
    const int lane = threadIdx.x;
    const int ct   = blockIdx.x;       // 0..23 -> 64-wide d-tile
    const int c    = blockIdx.y;       // 0..NF-1
    const int nd0  = ct * 64;
    const int l    = nd0 / DD;
    const int d0   = nd0 - l * DD;

    const int col  = lane & 31;
    const int krow = (lane >> 5) << 3; // 0 or 8

    // float2 view of weight row, starting at d0; lane covers d = d0+2*col,+1
    const float2* __restrict__ wbase2 =
        (const float2*)(weight + (size_t)l * FF * DD + d0) + col;

    float16 acc0, acc1;
#pragma unroll
    for (int i = 0; i < 16; ++i) { acc0[i] = 0.f; acc1[i] = 0.f; }

    const int s0 = c * KS;
    for (int s = s0; s < s0 + KS; ++s) {
        uint4 av = aprep[(size_t)s * 64 + lane];
        short8 a8 = __builtin_bit_cast(short8, av);

        const float2* __restrict__ wr2 =
            wbase2 + (size_t)(s * 16 + krow) * (DD / 2);
        float2 wv[8];
#pragma unroll
        for (int j = 0; j < 8; ++j)
            wv[j] = wr2[j * (DD / 2)];   // 512B contiguous per instruction

        short8 b0, b1;
#pragma unroll
        for (int jj = 0; jj < 8; ++jj) {
            b0[jj] = (short)bf16rne(wv[jj].x);   // even d tile
            b1[jj] = (short)bf16rne(wv[jj].y);   // odd  d tile
        }
        acc0 = __builtin_amdgcn_mfma_f32_32x32x16_bf16(a8, b0, acc0, 0, 0, 0);
        acc1 = __builtin_amdgcn_mfma_f32_32x32x16_bf16(a8, b1, acc1, 0, 0, 0);
    }

    // write: lane covers (d0+2*col, d0+2*col+1) as one float2 -> coalesced
    float2* __restrict__ pp2 =
        (float2*)(partials + (size_t)c * BL + (size_t)(l * DD + d0)) + col;
#pragma unroll
    for (int r = 0; r < 16; ++r) {
        int b = (r & 3) + 8 * (r >> 2) + 4 * (lane >> 5);
        pp2[(size_t)b * (LD / 2)] = make_float2(acc0[r], acc1[r]);
    }
}

// Stage 2 (fused): out[o] = bias[ld] + sum_c partials[c][o]
__global__ __launch_bounds__(256) void cc_stage2(
    const float* __restrict__ partials,
    const float* __restrict__ bias,
    float* __restrict__ out)
{
    int o = blockIdx.x * 256 + threadIdx.x;   // 0 .. BL-1
    if (o >= BL) return;
    int b  = o / LD;
    int ld = o - b * LD;
    float s = bias[ld];
    const float* __restrict__ p = partials + o;
#pragma unroll 16
    for (int c = 0; c < NF; ++c, p += BL)
        s += *p;
    out[o] = s;
}

// Correctness-only fallback if workspace is too small (fp32 path).
__global__ __launch_bounds__(256) void cc_direct(
    const float* __restrict__ f,
    const float* __restrict__ weight,
    const float* __restrict__ bias,
    float* __restrict__ out)
{
    int o = blockIdx.x * 256 + threadIdx.x;
    if (o >= BL) return;
    int b  = o / LD;
    int ld = o - b * LD;
    int l  = ld / DD;
    int d  = ld - l * DD;
    float s = bias[ld];
    const float* wp = weight + (size_t)l * FF * DD + d;
    const float* fp = f + (size_t)b * FF;
    for (int fi = 0; fi < FF; ++fi)
        s = fmaf(fp[fi], wp[(size_t)fi * DD], s);
    out[o] = s;
}

extern "C" void kernel_launch(void* const* d_in, const int* in_sizes, int n_in,
                              void* d_out, int out_size, void* d_ws, size_t ws_size,
                              hipStream_t stream)
{
    const float* f      = (const float*)d_in[0];   // 32 x 65536
    const float* weight = (const float*)d_in[1];   // 2 x 65536 x 768
    const float* bias   = (const float*)d_in[2];   // 2 x 768
    float* out          = (float*)d_out;           // 32 x 2 x 768

    const size_t need = APREP_BYTES + (size_t)NF * CHUNK_BYTES;
    if (ws_size < need) {
        cc_direct<<<(BL + 255) / 256, 256, 0, stream>>>(f, weight, bias, out);
        return;
    }

    uint4* aprep    = (uint4*)d_ws;
    float* partials = (float*)((char*)d_ws + APREP_BYTES);

    cc_prep_a<<<(NSTEPS * 64 + 255) / 256, 256, 0, stream>>>(
        (const float4*)f, aprep);

    dim3 grid1(24, NF);
    cc_mfma<<<grid1, 64, 0, stream>>>(aprep, weight, partials);

    cc_stage2<<<(BL + 255) / 256, 256, 0, stream>>>(partials, bias, out);
}

// Round 20
// 100.603 us; speedup vs baseline: 1.0274x; 1.0274x over previous
//
#include <hip/hip_runtime.h>

// Problem constants: B=32, L=2, F=65536, D=768
#define BB 32
#define LL 2
#define FF 65536
#define DD 768
#define F4 (FF / 4)        // 16384 float4 per f row
#define LD (LL * DD)       // 1536
#define BL (BB * LD)       // 49152 outputs

#define NSTEPS (FF / 16)   // 4096 K16-steps
#define APREP_BYTES ((size_t)NSTEPS * 64 * 16)      // 4 MB
#define CHUNK_BYTES ((size_t)BL * sizeof(float))    // 196608 B
#define NF 128             // F-chunks (split-K); grid (NF, 2) = 256 blocks
#define KS (NSTEPS / NF)   // 32 K16-steps per chunk

typedef __attribute__((ext_vector_type(8)))  short short8;   // 8 bf16 (4 VGPR)
typedef __attribute__((ext_vector_type(16))) float float16;  // 16 fp32 acc

// fp32 -> bf16 round-to-nearest-even (finite inputs)
static __device__ __forceinline__ unsigned bf16rne(float x)
{
    unsigned u = __float_as_uint(x);
    return (u + 0x7fffu + ((u >> 16) & 1u)) >> 16;
}
static __device__ __forceinline__ unsigned packbf(float a, float b)
{
    return bf16rne(a) | (bf16rne(b) << 16);
}

// Prep: build A-fragments. aprep[s][lane] (uint4) = 8 bf16 of
// A[row = lane&31][k = s*16 + (lane>>5)*8 + j], j=0..7, A[b][k] = f[b][k].
__global__ __launch_bounds__(256) void cc_prep_a(
    const float4* __restrict__ f4,     // [32][16384]
    uint4* __restrict__ aprep)         // [4096][64]
{
    int t = blockIdx.x * 256 + threadIdx.x;      // 0 .. 4096*64-1
    if (t >= NSTEPS * 64) return;
    int s = t >> 6;
    int l = t & 63;
    int b = l & 31;
    int k0 = s * 16 + ((l >> 5) << 3);           // multiple of 8
    float4 fa = f4[(size_t)b * F4 + (k0 >> 2)];
    float4 fb = f4[(size_t)b * F4 + (k0 >> 2) + 1];
    uint4 u;
    u.x = packbf(fa.x, fa.y);
    u.y = packbf(fa.z, fa.w);
    u.z = packbf(fb.x, fb.y);
    u.w = packbf(fb.z, fb.w);
    aprep[t] = u;
}

// Stage 1: MFMA partial GEMM with LINEAR weight streaming.
// grid = (NF, 2); block = 512 (8 waves). Block tile: M=32 x N=768 (full row),
// K-chunk = KS*16 = 512.  Per K16-step:
//   - stage 16 full rows (48 KB CONTIGUOUS) into LDS via 48 global_load_lds
//     dwordx4 (1 KB/instr, fill-kernel-identical address stream, no VGPR trip)
//   - each wave: 3 n-tiles (d = 96*wv + 32*i + col); B-frag = 8 ds_read_b32
//     column gathers (banks = d mod 32 -> conflict-free) + bf16 cvt + verified
//     mfma_f32_32x32x16_bf16.
// Serial stage->compute, 2 barriers/step (drain = intended BW throttle).
// LDS 48 KB static; 256 blocks = 1/CU exactly; VGPR ~85 -> no spill risk.
// C/D layout (verified): col = lane&31, row = (r&3) + 8*(r>>2) + 4*(lane>>5).
__global__ __launch_bounds__(512, 2) void cc_mfma(
    const uint4* __restrict__ aprep,   // [4096][64]
    const float* __restrict__ weight,  // [2][65536][768]
    float* __restrict__ partials)      // [NF][32][1536]
{
    __shared__ float lbuf[16 * DD];    // 48 KB: 16 staged rows

    const int tid  = threadIdx.x;
    const int lane = tid & 63;
    const int wv   = tid >> 6;         // 0..7
    const int c    = blockIdx.x;       // 0..NF-1
    const int l    = blockIdx.y;       // 0..1
    const int col  = lane & 31;
    const int half = lane >> 5;

    // chunk base: rows [c*KS*16, (c+1)*KS*16) of W[l]
    const float4* __restrict__ wchunk =
        (const float4*)(weight + ((size_t)l * FF + (size_t)c * (KS * 16)) * DD);
    float4* lb4 = (float4*)lbuf;

    const uint4* __restrict__ ap = aprep + (size_t)c * KS * 64 + lane;

    float16 acc[3];
#pragma unroll
    for (int i = 0; i < 3; ++i)
#pragma unroll
        for (int r = 0; r < 16; ++r) acc[i][r] = 0.f;

    for (int s = 0; s < KS; ++s) {
        __syncthreads();               // all ds_reads of prev step done
        const float4* __restrict__ gsrc = wchunk + (size_t)s * 3072;
#pragma unroll
        for (int t = 0; t < 6; ++t) {
            int idx = t * 512 + tid;   // wave-uniform LDS base + lane*16
            __builtin_amdgcn_global_load_lds(
                (const __attribute__((address_space(1))) void*)(gsrc + idx),
                (__attribute__((address_space(3))) void*)(lb4 + idx),
                16, 0, 0);
        }
        uint4 av = ap[(size_t)s * 64]; // A-frag (L2/L3), drains with the glls
        __syncthreads();               // compiler drains vmcnt before barrier

        short8 a8 = __builtin_bit_cast(short8, av);
        const int rbase = half * 8;
#pragma unroll
        for (int i = 0; i < 3; ++i) {
            const int d = 96 * wv + 32 * i + col;
            float w[8];
#pragma unroll
            for (int j = 0; j < 8; ++j)
                w[j] = lbuf[(rbase + j) * DD + d];   // conflict-free columns
            short8 b8;
#pragma unroll
            for (int j = 0; j < 8; ++j)
                b8[j] = (short)bf16rne(w[j]);
            acc[i] = __builtin_amdgcn_mfma_f32_32x32x16_bf16(a8, b8, acc[i], 0, 0, 0);
        }
    }

    float* __restrict__ pp = partials + (size_t)c * BL + (size_t)l * DD;
#pragma unroll
    for (int r = 0; r < 16; ++r) {
        int b = (r & 3) + 8 * (r >> 2) + 4 * half;
        float* rowp = pp + (size_t)b * LD + 96 * wv + col;
        rowp[0]  = acc[0][r];
        rowp[32] = acc[1][r];
        rowp[64] = acc[2][r];
    }
}

// Stage 2 (fused): out[o] = bias[ld] + sum_c partials[c][o]
__global__ __launch_bounds__(256) void cc_stage2(
    const float* __restrict__ partials,
    const float* __restrict__ bias,
    float* __restrict__ out)
{
    int o = blockIdx.x * 256 + threadIdx.x;   // 0 .. BL-1
    if (o >= BL) return;
    int b  = o / LD;
    int ld = o - b * LD;
    float s = bias[ld];
    const float* __restrict__ p = partials + o;
#pragma unroll 16
    for (int c = 0; c < NF; ++c, p += BL)
        s += *p;
    out[o] = s;
}

// Correctness-only fallback if workspace is too small (fp32 path).
__global__ __launch_bounds__(256) void cc_direct(
    const float* __restrict__ f,
    const float* __restrict__ weight,
    const float* __restrict__ bias,
    float* __restrict__ out)
{
    int o = blockIdx.x * 256 + threadIdx.x;
    if (o >= BL) return;
    int b  = o / LD;
    int ld = o - b * LD;
    int l  = ld / DD;
    int d  = ld - l * DD;
    float s = bias[ld];
    const float* wp = weight + (size_t)l * FF * DD + d;
    const float* fp = f + (size_t)b * FF;
    for (int fi = 0; fi < FF; ++fi)
        s = fmaf(fp[fi], wp[(size_t)fi * DD], s);
    out[o] = s;
}

extern "C" void kernel_launch(void* const* d_in, const int* in_sizes, int n_in,
                              void* d_out, int out_size, void* d_ws, size_t ws_size,
                              hipStream_t stream)
{
    const float* f      = (const float*)d_in[0];   // 32 x 65536
    const float* weight = (const float*)d_in[1];   // 2 x 65536 x 768
    const float* bias   = (const float*)d_in[2];   // 2 x 768
    float* out          = (float*)d_out;           // 32 x 2 x 768

    const size_t need = APREP_BYTES + (size_t)NF * CHUNK_BYTES;
    if (ws_size < need) {
        cc_direct<<<(BL + 255) / 256, 256, 0, stream>>>(f, weight, bias, out);
        return;
    }

    uint4* aprep    = (uint4*)d_ws;
    float* partials = (float*)((char*)d_ws + APREP_BYTES);

    cc_prep_a<<<(NSTEPS * 64 + 255) / 256, 256, 0, stream>>>(
        (const float4*)f, aprep);

    dim3 grid1(NF, LL);
    cc_mfma<<<grid1, 512, 0, stream>>>(aprep, weight, partials);

    cc_stage2<<<(BL + 255) / 256, 256, 0, stream>>>(partials, bias, out);
}